// Round 1
// baseline (587.250 us; speedup 1.0000x reference)
//
#include <hip/hip_runtime.h>
#include <math.h>

#define B_   16
#define C_   128
#define W_   128
#define HW_  16384

// workspace float offsets
#define OFF_SARR 0
#define OFF_GAP  128
#define OFF_FAVG 2176
#define OFF_CTX  4224
#define OFF_G    6272
#define OFF_CB   8320
#define OFF_WTS  10368
#define OFF_M    16384
#define OFF_S    (16384 + 262144)
#define OFF_SMAP (16384 + 2 * 262144)
// total ws use = OFF_SMAP + 4*262144 floats ~= 6.1 MB

__device__ __forceinline__ float wave_reduce_sum(float v) {
#pragma unroll
  for (int o = 32; o > 0; o >>= 1) v += __shfl_down(v, o, 64);
  return v;
}

// ---------- K0: DCT row-sum table: sarr[n] = sum_k 2*cos(pi*(2n+1)*k/256) ----------
__global__ void k0_sarr(float* __restrict__ sarr) {
  int w = threadIdx.x;  // 128 threads
  double a = 3.14159265358979323846 * (2.0 * w + 1.0) / 256.0;
  double s = 0.0;
  for (int k = 0; k < 128; ++k) s += cos(a * (double)k);
  sarr[w] = (float)(2.0 * s);
}

// ---------- K1: per-(b,c) plane: gap = mean(x), favg = mean(x*sh[y]*sw[x]) ----------
__global__ __launch_bounds__(256) void k1_planered(const float* __restrict__ x,
                                                   const float* __restrict__ sarr,
                                                   float* __restrict__ gap,
                                                   float* __restrict__ favg) {
  __shared__ float sL[128];
  __shared__ float buf[8];
  int tid = threadIdx.x;
  int bc = blockIdx.x;
  if (tid < 128) sL[tid] = sarr[tid];
  __syncthreads();
  const float* xp = x + (size_t)bc * HW_;
  float s0 = 0.f, s1 = 0.f;
  for (int i = tid << 2; i < HW_; i += 1024) {
    float4 v = *(const float4*)(xp + i);
    int y = i >> 7, xs = i & 127;
    float shy = sL[y];
    float d = v.x * sL[xs] + v.y * sL[xs + 1] + v.z * sL[xs + 2] + v.w * sL[xs + 3];
    s0 += v.x + v.y + v.z + v.w;
    s1 += shy * d;
  }
  s0 = wave_reduce_sum(s0);
  s1 = wave_reduce_sum(s1);
  int lane = tid & 63, wv = tid >> 6;
  if (lane == 0) { buf[wv] = s0; buf[4 + wv] = s1; }
  __syncthreads();
  if (tid == 0) {
    gap[bc]  = (buf[0] + buf[1] + buf[2] + buf[3]) * (1.f / 16384.f);
    favg[bc] = (buf[4] + buf[5] + buf[6] + buf[7]) * (1.f / 16384.f);
  }
}

// ---------- K2: mask logits m[b,p] = sum_c gcw[c]*x[b,c,p] + gcb ----------
__global__ __launch_bounds__(256) void k2_masklogit(const float* __restrict__ x,
                                                    const float* __restrict__ gcw,
                                                    const float* __restrict__ gcb,
                                                    float* __restrict__ m) {
  __shared__ float gl[128];
  int tid = threadIdx.x;
  int b = blockIdx.x >> 4;
  int chunk = blockIdx.x & 15;
  if (tid < 128) gl[tid] = gcw[tid];
  __syncthreads();
  int p0 = (chunk << 10) + (tid << 2);
  const float* xp = x + (size_t)b * C_ * HW_ + p0;
  float4 acc = make_float4(0.f, 0.f, 0.f, 0.f);
  for (int c = 0; c < 128; ++c) {
    float4 v = *(const float4*)(xp + (size_t)c * HW_);
    float wv = gl[c];
    acc.x = fmaf(wv, v.x, acc.x);
    acc.y = fmaf(wv, v.y, acc.y);
    acc.z = fmaf(wv, v.z, acc.z);
    acc.w = fmaf(wv, v.w, acc.w);
  }
  float bb = gcb[0];
  acc.x += bb; acc.y += bb; acc.z += bb; acc.w += bb;
  *(float4*)(m + b * HW_ + p0) = acc;
}

// ---------- K3: in-place softmax over m[b, 0:HW] ----------
__global__ __launch_bounds__(256) void k3_softmax(float* __restrict__ m) {
  __shared__ float buf[4];
  int b = blockIdx.x;
  int tid = threadIdx.x;
  float* mb = m + b * HW_;
  float mx = -1e30f;
  for (int i = tid << 2; i < HW_; i += 1024) {
    float4 v = *(const float4*)(mb + i);
    mx = fmaxf(mx, fmaxf(fmaxf(v.x, v.y), fmaxf(v.z, v.w)));
  }
#pragma unroll
  for (int o = 32; o > 0; o >>= 1) mx = fmaxf(mx, __shfl_down(mx, o, 64));
  if ((tid & 63) == 0) buf[tid >> 6] = mx;
  __syncthreads();
  if (tid == 0) buf[0] = fmaxf(fmaxf(buf[0], buf[1]), fmaxf(buf[2], buf[3]));
  __syncthreads();
  mx = buf[0];
  __syncthreads();
  float s = 0.f;
  for (int i = tid << 2; i < HW_; i += 1024) {
    float4 v = *(const float4*)(mb + i);
    float4 e;
    e.x = __expf(v.x - mx); e.y = __expf(v.y - mx);
    e.z = __expf(v.z - mx); e.w = __expf(v.w - mx);
    *(float4*)(mb + i) = e;
    s += e.x + e.y + e.z + e.w;
  }
  s = wave_reduce_sum(s);
  if ((tid & 63) == 0) buf[tid >> 6] = s;
  __syncthreads();
  if (tid == 0) buf[0] = buf[0] + buf[1] + buf[2] + buf[3];
  __syncthreads();
  float inv = 1.f / buf[0];
  for (int i = tid << 2; i < HW_; i += 1024) {
    float4 v = *(const float4*)(mb + i);
    v.x *= inv; v.y *= inv; v.z *= inv; v.w *= inv;
    *(float4*)(mb + i) = v;
  }
}

// ---------- K4: ctx[b,c] = sum_p x[b,c,p]*mask[b,p] ----------
__global__ __launch_bounds__(256) void k4_ctx(const float* __restrict__ x,
                                              const float* __restrict__ mask,
                                              float* __restrict__ ctx) {
  __shared__ float buf[4];
  int tid = threadIdx.x;
  int bc = blockIdx.x;
  int b = bc >> 7;
  const float* xp = x + (size_t)bc * HW_;
  const float* mp = mask + b * HW_;
  float s = 0.f;
  for (int i = tid << 2; i < HW_; i += 1024) {
    float4 v = *(const float4*)(xp + i);
    float4 mk = *(const float4*)(mp + i);
    s += v.x * mk.x + v.y * mk.y + v.z * mk.z + v.w * mk.w;
  }
  s = wave_reduce_sum(s);
  if ((tid & 63) == 0) buf[tid >> 6] = s;
  __syncthreads();
  if (tid == 0) ctx[bc] = buf[0] + buf[1] + buf[2] + buf[3];
}

// ---------- K5: tiny MLPs + LN + fusion scalars; outputs g[b,c], cb[b,o], wts ----------
__global__ __launch_bounds__(128) void k5_mlp(
    const float* __restrict__ gap, const float* __restrict__ favg,
    const float* __restrict__ ctx,
    const float* __restrict__ ca_w1, const float* __restrict__ ca_b1,
    const float* __restrict__ ca_w2, const float* __restrict__ ca_b2,
    const float* __restrict__ fa_w1, const float* __restrict__ fa_b1,
    const float* __restrict__ fa_w2, const float* __restrict__ fa_b2,
    const float* __restrict__ t1w, const float* __restrict__ t1b,
    const float* __restrict__ lng, const float* __restrict__ lnb,
    const float* __restrict__ t2w, const float* __restrict__ t2b,
    const float* __restrict__ alpha,
    const float* __restrict__ out_w, const float* __restrict__ out_b,
    float* __restrict__ g, float* __restrict__ cb, float* __restrict__ wts) {
  int b = blockIdx.x, t = threadIdx.x;
  __shared__ float gapL[128], favL[128], ctxL[128], hca[16], hfa[16], tl[8], dl[128];
  gapL[t] = gap[(b << 7) + t];
  favL[t] = favg[(b << 7) + t];
  ctxL[t] = ctx[(b << 7) + t];
  __syncthreads();
  if (t < 16) {
    float a = ca_b1[t], f = fa_b1[t];
    for (int c = 0; c < 128; ++c) {
      a += gapL[c] * ca_w1[t * 128 + c];
      f += favL[c] * fa_w1[t * 128 + c];
    }
    hca[t] = fmaxf(a, 0.f);
    hfa[t] = fmaxf(f, 0.f);
  }
  if (t < 8) {
    float v = t1b[t];
    for (int c = 0; c < 128; ++c) v += ctxL[c] * t1w[t * 128 + c];
    tl[t] = v;
  }
  __syncthreads();
  float mu = 0.f;
#pragma unroll
  for (int j = 0; j < 8; ++j) mu += tl[j];
  mu *= 0.125f;
  float var = 0.f;
#pragma unroll
  for (int j = 0; j < 8; ++j) { float d = tl[j] - mu; var += d * d; }
  var *= 0.125f;
  float rs = rsqrtf(var + 1e-5f);
  float a0 = alpha[0], a1 = alpha[1], a2 = alpha[2], a3 = alpha[3];
  float am = fmaxf(fmaxf(a0, a1), fmaxf(a2, a3));
  float e0 = __expf(a0 - am), e1 = __expf(a1 - am), e2 = __expf(a2 - am), e3 = __expf(a3 - am);
  float es = 1.f / (e0 + e1 + e2 + e3);
  float w0 = e0 * es, w1 = e1 * es, w2 = e2 * es, w3 = e3 * es;
  float cav = ca_b2[t], fav = fa_b2[t], c2 = t2b[t];
#pragma unroll
  for (int j = 0; j < 16; ++j) {
    cav += hca[j] * ca_w2[t * 16 + j];
    fav += hfa[j] * fa_w2[t * 16 + j];
  }
#pragma unroll
  for (int j = 0; j < 8; ++j) {
    float tn = fmaxf((tl[j] - mu) * rs * lng[j] + lnb[j], 0.f);
    c2 += tn * t2w[t * 8 + j];
  }
  cav = 1.f / (1.f + __expf(-cav));
  fav = 1.f / (1.f + __expf(-fav));
  g[(b << 7) + t] = w0 * cav + w2 * fav + w3;
  dl[t] = w3 * c2;
  __syncthreads();
  float s = out_b[t];
  for (int c = 0; c < 128; ++c) s += out_w[t * 128 + c] * dl[c];
  cb[(b << 7) + t] = s;
  if (b == 0 && t < 4) wts[t] = (t == 0) ? w0 : (t == 1) ? w1 : (t == 2) ? w2 : w3;
}

// ---------- K6: 9x9 conv over all channels -> smap partials (c-split x4) ----------
__global__ __launch_bounds__(256) void k6_conv(const float* __restrict__ x,
                                               const float* __restrict__ saw,
                                               float* __restrict__ smap_part) {
  __shared__ float tile[40 * 72];
  int tid = threadIdx.x;
  int t = blockIdx.x;       // 0..7 : ty = t>>1 (4 row tiles), tx = t&1 (2 col tiles)
  int b = blockIdx.y;
  int split = blockIdx.z;   // 0..3, 32 channels each
  int y0 = (t >> 1) << 5;
  int x0 = (t & 1) << 6;
  int rg = tid >> 4;        // 0..15 -> 2 output rows each
  int cg = tid & 15;        // 0..15 -> 4 output cols each
  int r0 = rg << 1;
  int px0 = cg << 2;
  float acc0[4] = {0.f, 0.f, 0.f, 0.f};
  float acc1[4] = {0.f, 0.f, 0.f, 0.f};
  const float* xb = x + (size_t)b * C_ * HW_;
  int c_lo = split << 5;
  for (int c = c_lo; c < c_lo + 32; ++c) {
    __syncthreads();
    const float* xc = xb + (size_t)c * HW_;
    for (int idx = tid; idx < 720; idx += 256) {
      int row = idx / 18, c4 = idx % 18;
      int gy = y0 - 4 + row;
      int gx = x0 - 4 + (c4 << 2);
      float4 v = make_float4(0.f, 0.f, 0.f, 0.f);
      if (gy >= 0 && gy < 128 && gx >= 0 && gx < 128)
        v = *(const float4*)(xc + gy * W_ + gx);
      *(float4*)(tile + row * 72 + (c4 << 2)) = v;
    }
    __syncthreads();
    const float* wrow = saw + c * 81;
    float rb[2][12];
    {
      const float* tp = tile + r0 * 72 + px0;
      float4 u0 = *(const float4*)tp, u1 = *(const float4*)(tp + 4), u2 = *(const float4*)(tp + 8);
      rb[0][0] = u0.x; rb[0][1] = u0.y; rb[0][2] = u0.z; rb[0][3] = u0.w;
      rb[0][4] = u1.x; rb[0][5] = u1.y; rb[0][6] = u1.z; rb[0][7] = u1.w;
      rb[0][8] = u2.x; rb[0][9] = u2.y; rb[0][10] = u2.z; rb[0][11] = u2.w;
    }
#pragma unroll
    for (int dy = 0; dy < 9; ++dy) {
      int cur = dy & 1, nxt = cur ^ 1;
      const float* tp = tile + (r0 + dy + 1) * 72 + px0;
      float4 u0 = *(const float4*)tp, u1 = *(const float4*)(tp + 4), u2 = *(const float4*)(tp + 8);
      rb[nxt][0] = u0.x; rb[nxt][1] = u0.y; rb[nxt][2] = u0.z; rb[nxt][3] = u0.w;
      rb[nxt][4] = u1.x; rb[nxt][5] = u1.y; rb[nxt][6] = u1.z; rb[nxt][7] = u1.w;
      rb[nxt][8] = u2.x; rb[nxt][9] = u2.y; rb[nxt][10] = u2.z; rb[nxt][11] = u2.w;
#pragma unroll
      for (int dx = 0; dx < 9; ++dx) {
        float wv = wrow[dy * 9 + dx];
#pragma unroll
        for (int j = 0; j < 4; ++j) {
          acc0[j] = fmaf(wv, rb[cur][dx + j], acc0[j]);
          acc1[j] = fmaf(wv, rb[nxt][dx + j], acc1[j]);
        }
      }
    }
  }
  float* op = smap_part + ((size_t)(split * B_ + b)) * HW_ + (y0 + r0) * W_ + x0 + px0;
  *(float4*)op = make_float4(acc0[0], acc0[1], acc0[2], acc0[3]);
  *(float4*)(op + W_) = make_float4(acc1[0], acc1[1], acc1[2], acc1[3]);
}

// ---------- K6b: s[b,p] = wts[1] * sigmoid(sum_parts + sa_b) ----------
__global__ __launch_bounds__(256) void k6b_gate(const float* __restrict__ smap_part,
                                                const float* __restrict__ wts,
                                                const float* __restrict__ sab,
                                                float* __restrict__ s) {
  int i = (blockIdx.x * 256 + threadIdx.x) << 2;
  float w1 = wts[1];
  float bb = sab[0];
  float4 a = *(const float4*)(smap_part + i);
  float4 b4 = *(const float4*)(smap_part + 262144 + i);
  float4 c4 = *(const float4*)(smap_part + 2 * 262144 + i);
  float4 d4 = *(const float4*)(smap_part + 3 * 262144 + i);
  float4 r;
  r.x = w1 / (1.f + __expf(-(a.x + b4.x + c4.x + d4.x + bb)));
  r.y = w1 / (1.f + __expf(-(a.y + b4.y + c4.y + d4.y + bb)));
  r.z = w1 / (1.f + __expf(-(a.z + b4.z + c4.z + d4.z + bb)));
  r.w = w1 / (1.f + __expf(-(a.w + b4.w + c4.w + d4.w + bb)));
  *(float4*)(s + i) = r;
}

// ---------- K7: out[b,o,p] = sum_c W[o,c]*x[b,c,p]*(g[b,c]+s[b,p]) + cb[b,o] ----------
__global__ __launch_bounds__(256, 2) void k7_gemm(const float* __restrict__ x,
                                                  const float* __restrict__ w,
                                                  const float* __restrict__ g,
                                                  const float* __restrict__ s,
                                                  const float* __restrict__ cb,
                                                  float* __restrict__ out) {
  __shared__ float wT[64 * 128];  // [c_local][swizzled o], chunk-XOR swizzle
  __shared__ float xm[64 * 128];  // [c_local][p]
  int tid = threadIdx.x;
  int b = blockIdx.x >> 7;
  int pt = blockIdx.x & 127;
  int p0 = pt << 7;
  const float* xb = x + (size_t)b * C_ * HW_ + p0;
  const float* sb = s + b * HW_ + p0;
  int pg = tid & 15, og = tid >> 4;
  int o0 = og << 3;
  int ppA = pg << 2;
  int ppB = 64 + (pg << 2);
  float acc[8][8];
#pragma unroll
  for (int i = 0; i < 8; ++i)
#pragma unroll
    for (int j = 0; j < 8; ++j) acc[i][j] = 0.f;
  int sp4 = (tid & 31) << 2;
  float4 sv = *(const float4*)(sb + sp4);
  int crow = tid >> 5;   // 0..7
  int wc4 = tid & 15;    // wT stage: f4 index along c
  int wor = tid >> 4;    // wT stage: o row offset
  for (int chunk = 0; chunk < 2; ++chunk) {
    int cbase = chunk << 6;
    __syncthreads();
#pragma unroll
    for (int pass = 0; pass < 8; ++pass) {
      // stage xm: xmod = x * (g[c] + s[p])
      int c = cbase + (pass << 3) + crow;
      float4 v = *(const float4*)(xb + (size_t)c * HW_ + sp4);
      float gc = g[(b << 7) + c];
      float4 r;
      r.x = v.x * (gc + sv.x);
      r.y = v.y * (gc + sv.y);
      r.z = v.z * (gc + sv.z);
      r.w = v.w * (gc + sv.w);
      *(float4*)(xm + ((c - cbase) << 7) + sp4) = r;
      // stage wT transposed with 16B-chunk XOR swizzle: q' = (o>>2) ^ (c_local>>2)
      int o = (pass << 4) + wor;
      float4 wv = *(const float4*)(w + (o << 7) + cbase + (wc4 << 2));
      int qp = (o >> 2) ^ wc4;
      int ob = o & 3;
      int cl = wc4 << 2;
      wT[(cl + 0) * 128 + (qp << 2) + ob] = wv.x;
      wT[(cl + 1) * 128 + (qp << 2) + ob] = wv.y;
      wT[(cl + 2) * 128 + (qp << 2) + ob] = wv.z;
      wT[(cl + 3) * 128 + (qp << 2) + ob] = wv.w;
    }
    __syncthreads();
#pragma unroll 4
    for (int cl = 0; cl < 64; ++cl) {
      int K = cl >> 2;
      const float* wrow = wT + (cl << 7);
      const float* xrow = xm + (cl << 7);
      float4 wa = *(const float4*)(wrow + ((((og << 1)) ^ K) << 2));
      float4 wb = *(const float4*)(wrow + ((((og << 1) | 1) ^ K) << 2));
      float4 xa = *(const float4*)(xrow + ppA);
      float4 xb4 = *(const float4*)(xrow + ppB);
      float wv[8] = {wa.x, wa.y, wa.z, wa.w, wb.x, wb.y, wb.z, wb.w};
      float xv[8] = {xa.x, xa.y, xa.z, xa.w, xb4.x, xb4.y, xb4.z, xb4.w};
#pragma unroll
      for (int i = 0; i < 8; ++i)
#pragma unroll
        for (int j = 0; j < 8; ++j) acc[i][j] = fmaf(wv[i], xv[j], acc[i][j]);
    }
  }
  size_t obase = ((size_t)((b << 7) + o0)) * HW_ + p0;
#pragma unroll
  for (int i = 0; i < 8; ++i) {
    float cv = cb[(b << 7) + o0 + i];
    float4 r0 = make_float4(acc[i][0] + cv, acc[i][1] + cv, acc[i][2] + cv, acc[i][3] + cv);
    float4 r1 = make_float4(acc[i][4] + cv, acc[i][5] + cv, acc[i][6] + cv, acc[i][7] + cv);
    *(float4*)(out + obase + (size_t)i * HW_ + ppA) = r0;
    *(float4*)(out + obase + (size_t)i * HW_ + ppB) = r1;
  }
}

extern "C" void kernel_launch(void* const* d_in, const int* in_sizes, int n_in,
                              void* d_out, int out_size, void* d_ws, size_t ws_size,
                              hipStream_t stream) {
  const float* x       = (const float*)d_in[0];
  const float* ca_w1   = (const float*)d_in[1];
  const float* ca_b1   = (const float*)d_in[2];
  const float* ca_w2   = (const float*)d_in[3];
  const float* ca_b2   = (const float*)d_in[4];
  const float* sa_w    = (const float*)d_in[5];
  const float* sa_b    = (const float*)d_in[6];
  const float* fa_w1   = (const float*)d_in[7];
  const float* fa_b1   = (const float*)d_in[8];
  const float* fa_w2   = (const float*)d_in[9];
  const float* fa_b2   = (const float*)d_in[10];
  const float* gc_mw   = (const float*)d_in[11];
  const float* gc_mb   = (const float*)d_in[12];
  const float* gc_t1w  = (const float*)d_in[13];
  const float* gc_t1b  = (const float*)d_in[14];
  const float* gc_lng  = (const float*)d_in[15];
  const float* gc_lnb  = (const float*)d_in[16];
  const float* gc_t2w  = (const float*)d_in[17];
  const float* gc_t2b  = (const float*)d_in[18];
  const float* alpha   = (const float*)d_in[19];
  const float* out_w   = (const float*)d_in[20];
  const float* out_b   = (const float*)d_in[21];
  float* out = (float*)d_out;
  float* ws = (float*)d_ws;

  float* sarr = ws + OFF_SARR;
  float* gap  = ws + OFF_GAP;
  float* favg = ws + OFF_FAVG;
  float* ctx  = ws + OFF_CTX;
  float* g    = ws + OFF_G;
  float* cb   = ws + OFF_CB;
  float* wts  = ws + OFF_WTS;
  float* m    = ws + OFF_M;
  float* s    = ws + OFF_S;
  float* smap = ws + OFF_SMAP;

  k0_sarr<<<1, 128, 0, stream>>>(sarr);
  k1_planered<<<2048, 256, 0, stream>>>(x, sarr, gap, favg);
  k2_masklogit<<<256, 256, 0, stream>>>(x, gc_mw, gc_mb, m);
  k3_softmax<<<16, 256, 0, stream>>>(m);
  k4_ctx<<<2048, 256, 0, stream>>>(x, m, ctx);
  k5_mlp<<<16, 128, 0, stream>>>(gap, favg, ctx, ca_w1, ca_b1, ca_w2, ca_b2,
                                 fa_w1, fa_b1, fa_w2, fa_b2, gc_t1w, gc_t1b,
                                 gc_lng, gc_lnb, gc_t2w, gc_t2b, alpha,
                                 out_w, out_b, g, cb, wts);
  k6_conv<<<dim3(8, 16, 4), 256, 0, stream>>>(x, sa_w, smap);
  k6b_gate<<<256, 256, 0, stream>>>(smap, wts, sa_b, s);
  k7_gemm<<<2048, 256, 0, stream>>>(x, out_w, g, s, cb, out);
}

// Round 2
// 542.743 us; speedup vs baseline: 1.0820x; 1.0820x over previous
//
#include <hip/hip_runtime.h>
#include <math.h>

#define B_   16
#define C_   128
#define W_   128
#define HW_  16384

// workspace float offsets
#define OFF_SARR 0
#define OFF_GAP  128
#define OFF_FAVG 2176
#define OFF_CTX  4224
#define OFF_G    6272
#define OFF_CB   8320
#define OFF_WTS  10368
#define OFF_PMAX 10496
#define OFF_PSUM 10752
#define OFF_SMX  11008
#define OFF_SINV 11024
#define OFF_M    16384
#define OFF_S    (16384 + 262144)
#define OFF_SMAP (16384 + 2 * 262144)

__device__ __forceinline__ float wave_reduce_sum(float v) {
#pragma unroll
  for (int o = 32; o > 0; o >>= 1) v += __shfl_down(v, o, 64);
  return v;
}

// ---------- K0: DCT row-sum table, closed form ----------
// sarr[n] = 2*sum_{k=0}^{127} cos(pi*(2n+1)k/256)
//         = 2*sin(64a)*cos(63.5a)/sin(0.5a),  a = pi(2n+1)/256
__global__ void k0_sarr(float* __restrict__ sarr) {
  int n = threadIdx.x;  // 128 threads
  double a = 3.14159265358979323846 * (2.0 * n + 1.0) / 256.0;
  double v = 2.0 * sin(64.0 * a) * cos(63.5 * a) / sin(0.5 * a);
  sarr[n] = (float)v;
}

// ---------- K1: per-(b,c) plane: gap = mean(x), favg = mean(x*sh[y]*sw[x]) ----------
__global__ __launch_bounds__(256) void k1_planered(const float* __restrict__ x,
                                                   const float* __restrict__ sarr,
                                                   float* __restrict__ gap,
                                                   float* __restrict__ favg) {
  __shared__ float sL[128];
  __shared__ float buf[8];
  int tid = threadIdx.x;
  int bc = blockIdx.x;
  if (tid < 128) sL[tid] = sarr[tid];
  __syncthreads();
  const float* xp = x + (size_t)bc * HW_;
  float s0 = 0.f, s1 = 0.f;
  for (int i = tid << 2; i < HW_; i += 1024) {
    float4 v = *(const float4*)(xp + i);
    int y = i >> 7, xs = i & 127;
    float shy = sL[y];
    float d = v.x * sL[xs] + v.y * sL[xs + 1] + v.z * sL[xs + 2] + v.w * sL[xs + 3];
    s0 += v.x + v.y + v.z + v.w;
    s1 += shy * d;
  }
  s0 = wave_reduce_sum(s0);
  s1 = wave_reduce_sum(s1);
  int lane = tid & 63, wv = tid >> 6;
  if (lane == 0) { buf[wv] = s0; buf[4 + wv] = s1; }
  __syncthreads();
  if (tid == 0) {
    gap[bc]  = (buf[0] + buf[1] + buf[2] + buf[3]) * (1.f / 16384.f);
    favg[bc] = (buf[4] + buf[5] + buf[6] + buf[7]) * (1.f / 16384.f);
  }
}

// ---------- K2: mask logits m[b,p] = sum_c gcw[c]*x[b,c,p] + gcb ----------
__global__ __launch_bounds__(256) void k2_masklogit(const float* __restrict__ x,
                                                    const float* __restrict__ gcw,
                                                    const float* __restrict__ gcb,
                                                    float* __restrict__ m) {
  __shared__ float gl[128];
  int tid = threadIdx.x;
  int b = blockIdx.x >> 4;
  int chunk = blockIdx.x & 15;
  if (tid < 128) gl[tid] = gcw[tid];
  __syncthreads();
  int p0 = (chunk << 10) + (tid << 2);
  const float* xp = x + (size_t)b * C_ * HW_ + p0;
  float4 acc = make_float4(0.f, 0.f, 0.f, 0.f);
  for (int c = 0; c < 128; ++c) {
    float4 v = *(const float4*)(xp + (size_t)c * HW_);
    float wv = gl[c];
    acc.x = fmaf(wv, v.x, acc.x);
    acc.y = fmaf(wv, v.y, acc.y);
    acc.z = fmaf(wv, v.z, acc.z);
    acc.w = fmaf(wv, v.w, acc.w);
  }
  float bb = gcb[0];
  acc.x += bb; acc.y += bb; acc.z += bb; acc.w += bb;
  *(float4*)(m + b * HW_ + p0) = acc;
}

// ---------- K3a: per-(b,chunk) partial max / sum-exp ----------
__global__ __launch_bounds__(256) void k3a_part(const float* __restrict__ m,
                                                float* __restrict__ pmax,
                                                float* __restrict__ psum) {
  __shared__ float buf[8];
  int blk = blockIdx.x;  // b*16 + chunk
  int tid = threadIdx.x;
  float4 v = *(const float4*)(m + (blk << 10) + (tid << 2));
  float mx = fmaxf(fmaxf(v.x, v.y), fmaxf(v.z, v.w));
#pragma unroll
  for (int o = 32; o > 0; o >>= 1) mx = fmaxf(mx, __shfl_xor(mx, o, 64));
  int lane = tid & 63, wv = tid >> 6;
  if (lane == 0) buf[wv] = mx;
  __syncthreads();
  mx = fmaxf(fmaxf(buf[0], buf[1]), fmaxf(buf[2], buf[3]));
  float s = __expf(v.x - mx) + __expf(v.y - mx) + __expf(v.z - mx) + __expf(v.w - mx);
  s = wave_reduce_sum(s);
  if (lane == 0) buf[4 + wv] = s;
  __syncthreads();
  if (tid == 0) {
    pmax[blk] = mx;
    psum[blk] = buf[4] + buf[5] + buf[6] + buf[7];
  }
}

// ---------- K3b: combine 16 partials per b -> smx, sinv ----------
__global__ void k3b_comb(const float* __restrict__ pmax, const float* __restrict__ psum,
                         float* __restrict__ smx, float* __restrict__ sinv) {
  int tid = threadIdx.x;  // 256 threads: b = tid>>4, j = tid&15
  int b = tid >> 4, j = tid & 15;
  float mx = pmax[tid];
  float sm = psum[tid];
  float gmx = mx;
#pragma unroll
  for (int o = 8; o > 0; o >>= 1) gmx = fmaxf(gmx, __shfl_xor(gmx, o, 64));
  float e = sm * __expf(mx - gmx);
#pragma unroll
  for (int o = 8; o > 0; o >>= 1) e += __shfl_xor(e, o, 64);
  if (j == 0) { smx[b] = gmx; sinv[b] = 1.f / e; }
}

// ---------- K3c: normalize in place: m = exp(m - smx)*sinv ----------
__global__ __launch_bounds__(256) void k3c_norm(float* __restrict__ m,
                                                const float* __restrict__ smx,
                                                const float* __restrict__ sinv) {
  int blk = blockIdx.x;
  int b = blk >> 4;
  int i = (blk << 10) + (threadIdx.x << 2);
  float mx = smx[b], inv = sinv[b];
  float4 v = *(const float4*)(m + i);
  v.x = __expf(v.x - mx) * inv;
  v.y = __expf(v.y - mx) * inv;
  v.z = __expf(v.z - mx) * inv;
  v.w = __expf(v.w - mx) * inv;
  *(float4*)(m + i) = v;
}

// ---------- K4: ctx[b,c] = sum_p x[b,c,p]*mask[b,p] ----------
__global__ __launch_bounds__(256) void k4_ctx(const float* __restrict__ x,
                                              const float* __restrict__ mask,
                                              float* __restrict__ ctx) {
  __shared__ float buf[4];
  int tid = threadIdx.x;
  int bc = blockIdx.x;
  int b = bc >> 7;
  const float* xp = x + (size_t)bc * HW_;
  const float* mp = mask + b * HW_;
  float s = 0.f;
  for (int i = tid << 2; i < HW_; i += 1024) {
    float4 v = *(const float4*)(xp + i);
    float4 mk = *(const float4*)(mp + i);
    s += v.x * mk.x + v.y * mk.y + v.z * mk.z + v.w * mk.w;
  }
  s = wave_reduce_sum(s);
  if ((tid & 63) == 0) buf[tid >> 6] = s;
  __syncthreads();
  if (tid == 0) ctx[bc] = buf[0] + buf[1] + buf[2] + buf[3];
}

// ---------- K5: tiny MLPs + LN + fusion scalars ----------
__global__ __launch_bounds__(128) void k5_mlp(
    const float* __restrict__ gap, const float* __restrict__ favg,
    const float* __restrict__ ctx,
    const float* __restrict__ ca_w1, const float* __restrict__ ca_b1,
    const float* __restrict__ ca_w2, const float* __restrict__ ca_b2,
    const float* __restrict__ fa_w1, const float* __restrict__ fa_b1,
    const float* __restrict__ fa_w2, const float* __restrict__ fa_b2,
    const float* __restrict__ t1w, const float* __restrict__ t1b,
    const float* __restrict__ lng, const float* __restrict__ lnb,
    const float* __restrict__ t2w, const float* __restrict__ t2b,
    const float* __restrict__ alpha,
    const float* __restrict__ out_w, const float* __restrict__ out_b,
    float* __restrict__ g, float* __restrict__ cb, float* __restrict__ wts) {
  int b = blockIdx.x, t = threadIdx.x;
  __shared__ float gapL[128], favL[128], ctxL[128], hca[16], hfa[16], tl[8], dl[128];
  gapL[t] = gap[(b << 7) + t];
  favL[t] = favg[(b << 7) + t];
  ctxL[t] = ctx[(b << 7) + t];
  __syncthreads();
  if (t < 16) {
    float a = ca_b1[t], f = fa_b1[t];
    for (int c = 0; c < 128; ++c) {
      a += gapL[c] * ca_w1[t * 128 + c];
      f += favL[c] * fa_w1[t * 128 + c];
    }
    hca[t] = fmaxf(a, 0.f);
    hfa[t] = fmaxf(f, 0.f);
  }
  if (t < 8) {
    float v = t1b[t];
    for (int c = 0; c < 128; ++c) v += ctxL[c] * t1w[t * 128 + c];
    tl[t] = v;
  }
  __syncthreads();
  float mu = 0.f;
#pragma unroll
  for (int j = 0; j < 8; ++j) mu += tl[j];
  mu *= 0.125f;
  float var = 0.f;
#pragma unroll
  for (int j = 0; j < 8; ++j) { float d = tl[j] - mu; var += d * d; }
  var *= 0.125f;
  float rs = rsqrtf(var + 1e-5f);
  float a0 = alpha[0], a1 = alpha[1], a2 = alpha[2], a3 = alpha[3];
  float am = fmaxf(fmaxf(a0, a1), fmaxf(a2, a3));
  float e0 = __expf(a0 - am), e1 = __expf(a1 - am), e2 = __expf(a2 - am), e3 = __expf(a3 - am);
  float es = 1.f / (e0 + e1 + e2 + e3);
  float w0 = e0 * es, w1 = e1 * es, w2 = e2 * es, w3 = e3 * es;
  float cav = ca_b2[t], fav = fa_b2[t], c2 = t2b[t];
#pragma unroll
  for (int j = 0; j < 16; ++j) {
    cav += hca[j] * ca_w2[t * 16 + j];
    fav += hfa[j] * fa_w2[t * 16 + j];
  }
#pragma unroll
  for (int j = 0; j < 8; ++j) {
    float tn = fmaxf((tl[j] - mu) * rs * lng[j] + lnb[j], 0.f);
    c2 += tn * t2w[t * 8 + j];
  }
  cav = 1.f / (1.f + __expf(-cav));
  fav = 1.f / (1.f + __expf(-fav));
  g[(b << 7) + t] = w0 * cav + w2 * fav + w3;
  dl[t] = w3 * c2;
  __syncthreads();
  float s = out_b[t];
  for (int c = 0; c < 128; ++c) s += out_w[t * 128 + c] * dl[c];
  cb[(b << 7) + t] = s;
  if (b == 0 && t < 4) wts[t] = (t == 0) ? w0 : (t == 1) ? w1 : (t == 2) ? w2 : w3;
}

// ---------- K6: 9x9 conv, c-split partials, double-buffered LDS ----------
// tile stride 76 floats (pad from 72), 2 buffers
template <int CPS>  // channels per split
__global__ __launch_bounds__(256) void k6_conv(const float* __restrict__ x,
                                               const float* __restrict__ saw,
                                               float* __restrict__ smap_part) {
  __shared__ float tile[2][40 * 76];
  int tid = threadIdx.x;
  int t = blockIdx.x;       // 0..7 : ty = t>>1 (4 row tiles), tx = t&1 (2 col tiles)
  int b = blockIdx.y;
  int split = blockIdx.z;
  int y0 = (t >> 1) << 5;
  int x0 = (t & 1) << 6;
  int rg = tid >> 4;        // 0..15 -> 2 output rows each
  int cg = tid & 15;        // 0..15 -> 4 output cols each
  int r0 = rg << 1;
  int px0 = cg << 2;
  float acc0[4] = {0.f, 0.f, 0.f, 0.f};
  float acc1[4] = {0.f, 0.f, 0.f, 0.f};
  const float* xb = x + (size_t)b * C_ * HW_;
  int c_lo = split * CPS;

  auto stage = [&](int bufi, int c) {
    const float* xc = xb + (size_t)c * HW_;
    float* tb = tile[bufi];
    for (int idx = tid; idx < 720; idx += 256) {
      int row = idx / 18, c4 = idx - row * 18;
      int gy = y0 - 4 + row;
      int gx = x0 - 4 + (c4 << 2);
      float4 v = make_float4(0.f, 0.f, 0.f, 0.f);
      if (gy >= 0 && gy < 128 && gx >= 0 && gx < 128)
        v = *(const float4*)(xc + gy * W_ + gx);
      *(float4*)(tb + row * 76 + (c4 << 2)) = v;
    }
  };

  stage(0, c_lo);
  for (int i = 0; i < CPS; ++i) {
    __syncthreads();  // stage of tile[i&1] complete; prior compute done
    if (i + 1 < CPS) stage((i + 1) & 1, c_lo + i + 1);
    const float* tb = tile[i & 1];
    const float* wrow = saw + (c_lo + i) * 81;
    float rb[2][12];
    {
      const float* tp = tb + r0 * 76 + px0;
      float4 u0 = *(const float4*)tp, u1 = *(const float4*)(tp + 4), u2 = *(const float4*)(tp + 8);
      rb[0][0] = u0.x; rb[0][1] = u0.y; rb[0][2] = u0.z; rb[0][3] = u0.w;
      rb[0][4] = u1.x; rb[0][5] = u1.y; rb[0][6] = u1.z; rb[0][7] = u1.w;
      rb[0][8] = u2.x; rb[0][9] = u2.y; rb[0][10] = u2.z; rb[0][11] = u2.w;
    }
#pragma unroll
    for (int dy = 0; dy < 9; ++dy) {
      int cur = dy & 1, nxt = cur ^ 1;
      const float* tp = tb + (r0 + dy + 1) * 76 + px0;
      float4 u0 = *(const float4*)tp, u1 = *(const float4*)(tp + 4), u2 = *(const float4*)(tp + 8);
      rb[nxt][0] = u0.x; rb[nxt][1] = u0.y; rb[nxt][2] = u0.z; rb[nxt][3] = u0.w;
      rb[nxt][4] = u1.x; rb[nxt][5] = u1.y; rb[nxt][6] = u1.z; rb[nxt][7] = u1.w;
      rb[nxt][8] = u2.x; rb[nxt][9] = u2.y; rb[nxt][10] = u2.z; rb[nxt][11] = u2.w;
#pragma unroll
      for (int dx = 0; dx < 9; ++dx) {
        float wv = wrow[dy * 9 + dx];
#pragma unroll
        for (int j = 0; j < 4; ++j) {
          acc0[j] = fmaf(wv, rb[cur][dx + j], acc0[j]);
          acc1[j] = fmaf(wv, rb[nxt][dx + j], acc1[j]);
        }
      }
    }
  }
  float* op = smap_part + ((size_t)(split * B_ + b)) * HW_ + (y0 + r0) * W_ + x0 + px0;
  *(float4*)op = make_float4(acc0[0], acc0[1], acc0[2], acc0[3]);
  *(float4*)(op + W_) = make_float4(acc1[0], acc1[1], acc1[2], acc1[3]);
}

// ---------- K6b: s[b,p] = wts[1] * sigmoid(sum_parts + sa_b) ----------
template <int NS>
__global__ __launch_bounds__(256) void k6b_gate(const float* __restrict__ smap_part,
                                                const float* __restrict__ wts,
                                                const float* __restrict__ sab,
                                                float* __restrict__ s) {
  int i = (blockIdx.x * 256 + threadIdx.x) << 2;
  float w1 = wts[1];
  float bb = sab[0];
  float4 a = *(const float4*)(smap_part + i);
#pragma unroll
  for (int j = 1; j < NS; ++j) {
    float4 t4 = *(const float4*)(smap_part + (size_t)j * 262144 + i);
    a.x += t4.x; a.y += t4.y; a.z += t4.z; a.w += t4.w;
  }
  float4 r;
  r.x = w1 / (1.f + __expf(-(a.x + bb)));
  r.y = w1 / (1.f + __expf(-(a.y + bb)));
  r.z = w1 / (1.f + __expf(-(a.z + bb)));
  r.w = w1 / (1.f + __expf(-(a.w + bb)));
  *(float4*)(s + i) = r;
}

// ---------- K7: out[b,o,p] = sum_c W[o,c]*x[b,c,p]*(g[b,c]+s[b,p]) + cb[b,o] ----------
__global__ __launch_bounds__(256, 2) void k7_gemm(const float* __restrict__ x,
                                                  const float* __restrict__ w,
                                                  const float* __restrict__ g,
                                                  const float* __restrict__ s,
                                                  const float* __restrict__ cb,
                                                  float* __restrict__ out) {
  __shared__ float wT[64 * 128];  // [c_local][swizzled o], chunk-XOR swizzle
  __shared__ float xm[64 * 128];  // [c_local][p]
  int tid = threadIdx.x;
  int b = blockIdx.x >> 7;
  int pt = blockIdx.x & 127;
  int p0 = pt << 7;
  const float* xb = x + (size_t)b * C_ * HW_ + p0;
  const float* sb = s + b * HW_ + p0;
  int pg = tid & 15, og = tid >> 4;
  int o0 = og << 3;
  int ppA = pg << 2;
  int ppB = 64 + (pg << 2);
  float acc[8][8];
#pragma unroll
  for (int i = 0; i < 8; ++i)
#pragma unroll
    for (int j = 0; j < 8; ++j) acc[i][j] = 0.f;
  int sp4 = (tid & 31) << 2;
  float4 sv = *(const float4*)(sb + sp4);
  int crow = tid >> 5;   // 0..7
  int wc4 = tid & 15;    // wT stage: f4 index along c
  int wor = tid >> 4;    // wT stage: o row offset
  for (int chunk = 0; chunk < 2; ++chunk) {
    int cbase = chunk << 6;
    __syncthreads();
#pragma unroll
    for (int pass = 0; pass < 8; ++pass) {
      int c = cbase + (pass << 3) + crow;
      float4 v = *(const float4*)(xb + (size_t)c * HW_ + sp4);
      float gc = g[(b << 7) + c];
      float4 r;
      r.x = v.x * (gc + sv.x);
      r.y = v.y * (gc + sv.y);
      r.z = v.z * (gc + sv.z);
      r.w = v.w * (gc + sv.w);
      *(float4*)(xm + ((c - cbase) << 7) + sp4) = r;
      int o = (pass << 4) + wor;
      float4 wv = *(const float4*)(w + (o << 7) + cbase + (wc4 << 2));
      int qp = (o >> 2) ^ wc4;
      int ob = o & 3;
      int cl = wc4 << 2;
      wT[(cl + 0) * 128 + (qp << 2) + ob] = wv.x;
      wT[(cl + 1) * 128 + (qp << 2) + ob] = wv.y;
      wT[(cl + 2) * 128 + (qp << 2) + ob] = wv.z;
      wT[(cl + 3) * 128 + (qp << 2) + ob] = wv.w;
    }
    __syncthreads();
#pragma unroll 4
    for (int cl = 0; cl < 64; ++cl) {
      int K = cl >> 2;
      const float* wrow = wT + (cl << 7);
      const float* xrow = xm + (cl << 7);
      float4 wa = *(const float4*)(wrow + ((((og << 1)) ^ K) << 2));
      float4 wb = *(const float4*)(wrow + ((((og << 1) | 1) ^ K) << 2));
      float4 xa = *(const float4*)(xrow + ppA);
      float4 xb4 = *(const float4*)(xrow + ppB);
      float wv[8] = {wa.x, wa.y, wa.z, wa.w, wb.x, wb.y, wb.z, wb.w};
      float xv[8] = {xa.x, xa.y, xa.z, xa.w, xb4.x, xb4.y, xb4.z, xb4.w};
#pragma unroll
      for (int i = 0; i < 8; ++i)
#pragma unroll
        for (int j = 0; j < 8; ++j) acc[i][j] = fmaf(wv[i], xv[j], acc[i][j]);
    }
  }
  size_t obase = ((size_t)((b << 7) + o0)) * HW_ + p0;
#pragma unroll
  for (int i = 0; i < 8; ++i) {
    float cv = cb[(b << 7) + o0 + i];
    float4 r0 = make_float4(acc[i][0] + cv, acc[i][1] + cv, acc[i][2] + cv, acc[i][3] + cv);
    float4 r1 = make_float4(acc[i][4] + cv, acc[i][5] + cv, acc[i][6] + cv, acc[i][7] + cv);
    *(float4*)(out + obase + (size_t)i * HW_ + ppA) = r0;
    *(float4*)(out + obase + (size_t)i * HW_ + ppB) = r1;
  }
}

extern "C" void kernel_launch(void* const* d_in, const int* in_sizes, int n_in,
                              void* d_out, int out_size, void* d_ws, size_t ws_size,
                              hipStream_t stream) {
  const float* x       = (const float*)d_in[0];
  const float* ca_w1   = (const float*)d_in[1];
  const float* ca_b1   = (const float*)d_in[2];
  const float* ca_w2   = (const float*)d_in[3];
  const float* ca_b2   = (const float*)d_in[4];
  const float* sa_w    = (const float*)d_in[5];
  const float* sa_b    = (const float*)d_in[6];
  const float* fa_w1   = (const float*)d_in[7];
  const float* fa_b1   = (const float*)d_in[8];
  const float* fa_w2   = (const float*)d_in[9];
  const float* fa_b2   = (const float*)d_in[10];
  const float* gc_mw   = (const float*)d_in[11];
  const float* gc_mb   = (const float*)d_in[12];
  const float* gc_t1w  = (const float*)d_in[13];
  const float* gc_t1b  = (const float*)d_in[14];
  const float* gc_lng  = (const float*)d_in[15];
  const float* gc_lnb  = (const float*)d_in[16];
  const float* gc_t2w  = (const float*)d_in[17];
  const float* gc_t2b  = (const float*)d_in[18];
  const float* alpha   = (const float*)d_in[19];
  const float* out_w   = (const float*)d_in[20];
  const float* out_b   = (const float*)d_in[21];
  float* out = (float*)d_out;
  float* ws = (float*)d_ws;

  float* sarr = ws + OFF_SARR;
  float* gap  = ws + OFF_GAP;
  float* favg = ws + OFF_FAVG;
  float* ctx  = ws + OFF_CTX;
  float* g    = ws + OFF_G;
  float* cb   = ws + OFF_CB;
  float* wts  = ws + OFF_WTS;
  float* pmax = ws + OFF_PMAX;
  float* psum = ws + OFF_PSUM;
  float* smx  = ws + OFF_SMX;
  float* sinv = ws + OFF_SINV;
  float* m    = ws + OFF_M;
  float* s    = ws + OFF_S;
  float* smap = ws + OFF_SMAP;

  // 8-split conv needs OFF_SMAP + 8*262144 floats of workspace
  size_t need8 = (size_t)(16384 + 10 * 262144) * sizeof(float);
  int use8 = (ws_size >= need8) ? 1 : 0;

  k0_sarr<<<1, 128, 0, stream>>>(sarr);
  k1_planered<<<2048, 256, 0, stream>>>(x, sarr, gap, favg);
  k2_masklogit<<<256, 256, 0, stream>>>(x, gc_mw, gc_mb, m);
  k3a_part<<<256, 256, 0, stream>>>(m, pmax, psum);
  k3b_comb<<<1, 256, 0, stream>>>(pmax, psum, smx, sinv);
  k3c_norm<<<256, 256, 0, stream>>>(m, smx, sinv);
  k4_ctx<<<2048, 256, 0, stream>>>(x, m, ctx);
  k5_mlp<<<16, 128, 0, stream>>>(gap, favg, ctx, ca_w1, ca_b1, ca_w2, ca_b2,
                                 fa_w1, fa_b1, fa_w2, fa_b2, gc_t1w, gc_t1b,
                                 gc_lng, gc_lnb, gc_t2w, gc_t2b, alpha,
                                 out_w, out_b, g, cb, wts);
  if (use8) {
    k6_conv<16><<<dim3(8, 16, 8), 256, 0, stream>>>(x, sa_w, smap);
    k6b_gate<8><<<256, 256, 0, stream>>>(smap, wts, sa_b, s);
  } else {
    k6_conv<32><<<dim3(8, 16, 4), 256, 0, stream>>>(x, sa_w, smap);
    k6b_gate<4><<<256, 256, 0, stream>>>(smap, wts, sa_b, s);
  }
  k7_gemm<<<2048, 256, 0, stream>>>(x, out_w, g, s, cb, out);
}

// Round 3
// 532.108 us; speedup vs baseline: 1.1036x; 1.0200x over previous
//
#include <hip/hip_runtime.h>
#include <math.h>

#define B_   16
#define C_   128
#define W_   128
#define HW_  16384

// workspace float offsets
#define OFF_SARR 0
#define OFF_GAP  128
#define OFF_FAVG 2176
#define OFF_CTX  4224
#define OFF_G    6272
#define OFF_CB   8320
#define OFF_WTS  10368
#define OFF_PMAX 10496
#define OFF_PSUM 10752
#define OFF_SMX  11008
#define OFF_SINV 11024
#define OFF_WT   16384
#define OFF_M    32768
#define OFF_S    (32768 + 262144)
#define OFF_SMAP (32768 + 2 * 262144)

__device__ __forceinline__ float wave_reduce_sum(float v) {
#pragma unroll
  for (int o = 32; o > 0; o >>= 1) v += __shfl_down(v, o, 64);
  return v;
}

// ---------- K0: DCT row-sum table, closed form ----------
__global__ void k0_sarr(float* __restrict__ sarr) {
  int n = threadIdx.x;  // 128 threads
  double a = 3.14159265358979323846 * (2.0 * n + 1.0) / 256.0;
  double v = 2.0 * sin(64.0 * a) * cos(63.5 * a) / sin(0.5 * a);
  sarr[n] = (float)v;
}

// ---------- K1: per-(b,c) plane: gap = mean(x), favg = mean(x*sh[y]*sw[x]) ----------
__global__ __launch_bounds__(256) void k1_planered(const float* __restrict__ x,
                                                   const float* __restrict__ sarr,
                                                   float* __restrict__ gap,
                                                   float* __restrict__ favg) {
  __shared__ float sL[128];
  __shared__ float buf[8];
  int tid = threadIdx.x;
  int bc = blockIdx.x;
  if (tid < 128) sL[tid] = sarr[tid];
  __syncthreads();
  const float* xp = x + (size_t)bc * HW_;
  float s0 = 0.f, s1 = 0.f;
  for (int i = tid << 2; i < HW_; i += 1024) {
    float4 v = *(const float4*)(xp + i);
    int y = i >> 7, xs = i & 127;
    float shy = sL[y];
    float d = v.x * sL[xs] + v.y * sL[xs + 1] + v.z * sL[xs + 2] + v.w * sL[xs + 3];
    s0 += v.x + v.y + v.z + v.w;
    s1 += shy * d;
  }
  s0 = wave_reduce_sum(s0);
  s1 = wave_reduce_sum(s1);
  int lane = tid & 63, wv = tid >> 6;
  if (lane == 0) { buf[wv] = s0; buf[4 + wv] = s1; }
  __syncthreads();
  if (tid == 0) {
    gap[bc]  = (buf[0] + buf[1] + buf[2] + buf[3]) * (1.f / 16384.f);
    favg[bc] = (buf[4] + buf[5] + buf[6] + buf[7]) * (1.f / 16384.f);
  }
}

// ---------- K2: mask logits m[b,p] = sum_c gcw[c]*x[b,c,p] + gcb ----------
__global__ __launch_bounds__(256) void k2_masklogit(const float* __restrict__ x,
                                                    const float* __restrict__ gcw,
                                                    const float* __restrict__ gcb,
                                                    float* __restrict__ m) {
  __shared__ float gl[128];
  int tid = threadIdx.x;
  int b = blockIdx.x >> 4;
  int chunk = blockIdx.x & 15;
  if (tid < 128) gl[tid] = gcw[tid];
  __syncthreads();
  int p0 = (chunk << 10) + (tid << 2);
  const float* xp = x + (size_t)b * C_ * HW_ + p0;
  float4 acc = make_float4(0.f, 0.f, 0.f, 0.f);
  for (int c = 0; c < 128; ++c) {
    float4 v = *(const float4*)(xp + (size_t)c * HW_);
    float wv = gl[c];
    acc.x = fmaf(wv, v.x, acc.x);
    acc.y = fmaf(wv, v.y, acc.y);
    acc.z = fmaf(wv, v.z, acc.z);
    acc.w = fmaf(wv, v.w, acc.w);
  }
  float bb = gcb[0];
  acc.x += bb; acc.y += bb; acc.z += bb; acc.w += bb;
  *(float4*)(m + b * HW_ + p0) = acc;
}

// ---------- K3a: per-(b,chunk) partial max / sum-exp ----------
__global__ __launch_bounds__(256) void k3a_part(const float* __restrict__ m,
                                                float* __restrict__ pmax,
                                                float* __restrict__ psum) {
  __shared__ float buf[8];
  int blk = blockIdx.x;  // b*16 + chunk
  int tid = threadIdx.x;
  float4 v = *(const float4*)(m + (blk << 10) + (tid << 2));
  float mx = fmaxf(fmaxf(v.x, v.y), fmaxf(v.z, v.w));
#pragma unroll
  for (int o = 32; o > 0; o >>= 1) mx = fmaxf(mx, __shfl_xor(mx, o, 64));
  int lane = tid & 63, wv = tid >> 6;
  if (lane == 0) buf[wv] = mx;
  __syncthreads();
  mx = fmaxf(fmaxf(buf[0], buf[1]), fmaxf(buf[2], buf[3]));
  float s = __expf(v.x - mx) + __expf(v.y - mx) + __expf(v.z - mx) + __expf(v.w - mx);
  s = wave_reduce_sum(s);
  if (lane == 0) buf[4 + wv] = s;
  __syncthreads();
  if (tid == 0) {
    pmax[blk] = mx;
    psum[blk] = buf[4] + buf[5] + buf[6] + buf[7];
  }
}

// ---------- K3b: combine 16 partials per b -> smx, sinv ----------
__global__ void k3b_comb(const float* __restrict__ pmax, const float* __restrict__ psum,
                         float* __restrict__ smx, float* __restrict__ sinv) {
  int tid = threadIdx.x;  // 256 threads: b = tid>>4, j = tid&15
  int b = tid >> 4, j = tid & 15;
  float mx = pmax[tid];
  float sm = psum[tid];
  float gmx = mx;
#pragma unroll
  for (int o = 8; o > 0; o >>= 1) gmx = fmaxf(gmx, __shfl_xor(gmx, o, 64));
  float e = sm * __expf(mx - gmx);
#pragma unroll
  for (int o = 8; o > 0; o >>= 1) e += __shfl_xor(e, o, 64);
  if (j == 0) { smx[b] = gmx; sinv[b] = 1.f / e; }
}

// ---------- K3c: normalize in place: m = exp(m - smx)*sinv ----------
__global__ __launch_bounds__(256) void k3c_norm(float* __restrict__ m,
                                                const float* __restrict__ smx,
                                                const float* __restrict__ sinv) {
  int blk = blockIdx.x;
  int b = blk >> 4;
  int i = (blk << 10) + (threadIdx.x << 2);
  float mx = smx[b], inv = sinv[b];
  float4 v = *(const float4*)(m + i);
  v.x = __expf(v.x - mx) * inv;
  v.y = __expf(v.y - mx) * inv;
  v.z = __expf(v.z - mx) * inv;
  v.w = __expf(v.w - mx) * inv;
  *(float4*)(m + i) = v;
}

// ---------- K4: ctx[b,c] = sum_p x[b,c,p]*mask[b,p] ----------
__global__ __launch_bounds__(256) void k4_ctx(const float* __restrict__ x,
                                              const float* __restrict__ mask,
                                              float* __restrict__ ctx) {
  __shared__ float buf[4];
  int tid = threadIdx.x;
  int bc = blockIdx.x;
  int b = bc >> 7;
  const float* xp = x + (size_t)bc * HW_;
  const float* mp = mask + b * HW_;
  float s = 0.f;
  for (int i = tid << 2; i < HW_; i += 1024) {
    float4 v = *(const float4*)(xp + i);
    float4 mk = *(const float4*)(mp + i);
    s += v.x * mk.x + v.y * mk.y + v.z * mk.z + v.w * mk.w;
  }
  s = wave_reduce_sum(s);
  if ((tid & 63) == 0) buf[tid >> 6] = s;
  __syncthreads();
  if (tid == 0) ctx[bc] = buf[0] + buf[1] + buf[2] + buf[3];
}

// ---------- K5: tiny MLPs + LN + fusion scalars ----------
__global__ __launch_bounds__(128) void k5_mlp(
    const float* __restrict__ gap, const float* __restrict__ favg,
    const float* __restrict__ ctx,
    const float* __restrict__ ca_w1, const float* __restrict__ ca_b1,
    const float* __restrict__ ca_w2, const float* __restrict__ ca_b2,
    const float* __restrict__ fa_w1, const float* __restrict__ fa_b1,
    const float* __restrict__ fa_w2, const float* __restrict__ fa_b2,
    const float* __restrict__ t1w, const float* __restrict__ t1b,
    const float* __restrict__ lng, const float* __restrict__ lnb,
    const float* __restrict__ t2w, const float* __restrict__ t2b,
    const float* __restrict__ alpha,
    const float* __restrict__ out_w, const float* __restrict__ out_b,
    float* __restrict__ g, float* __restrict__ cb, float* __restrict__ wts) {
  int b = blockIdx.x, t = threadIdx.x;
  __shared__ float gapL[128], favL[128], ctxL[128], hca[16], hfa[16], tl[8], dl[128];
  gapL[t] = gap[(b << 7) + t];
  favL[t] = favg[(b << 7) + t];
  ctxL[t] = ctx[(b << 7) + t];
  __syncthreads();
  if (t < 16) {
    float a = ca_b1[t], f = fa_b1[t];
    for (int c = 0; c < 128; ++c) {
      a += gapL[c] * ca_w1[t * 128 + c];
      f += favL[c] * fa_w1[t * 128 + c];
    }
    hca[t] = fmaxf(a, 0.f);
    hfa[t] = fmaxf(f, 0.f);
  }
  if (t < 8) {
    float v = t1b[t];
    for (int c = 0; c < 128; ++c) v += ctxL[c] * t1w[t * 128 + c];
    tl[t] = v;
  }
  __syncthreads();
  float mu = 0.f;
#pragma unroll
  for (int j = 0; j < 8; ++j) mu += tl[j];
  mu *= 0.125f;
  float var = 0.f;
#pragma unroll
  for (int j = 0; j < 8; ++j) { float d = tl[j] - mu; var += d * d; }
  var *= 0.125f;
  float rs = rsqrtf(var + 1e-5f);
  float a0 = alpha[0], a1 = alpha[1], a2 = alpha[2], a3 = alpha[3];
  float am = fmaxf(fmaxf(a0, a1), fmaxf(a2, a3));
  float e0 = __expf(a0 - am), e1 = __expf(a1 - am), e2 = __expf(a2 - am), e3 = __expf(a3 - am);
  float es = 1.f / (e0 + e1 + e2 + e3);
  float w0 = e0 * es, w1 = e1 * es, w2 = e2 * es, w3 = e3 * es;
  float cav = ca_b2[t], fav = fa_b2[t], c2 = t2b[t];
#pragma unroll
  for (int j = 0; j < 16; ++j) {
    cav += hca[j] * ca_w2[t * 16 + j];
    fav += hfa[j] * fa_w2[t * 16 + j];
  }
#pragma unroll
  for (int j = 0; j < 8; ++j) {
    float tn = fmaxf((tl[j] - mu) * rs * lng[j] + lnb[j], 0.f);
    c2 += tn * t2w[t * 8 + j];
  }
  cav = 1.f / (1.f + __expf(-cav));
  fav = 1.f / (1.f + __expf(-fav));
  g[(b << 7) + t] = w0 * cav + w2 * fav + w3;
  dl[t] = w3 * c2;
  __syncthreads();
  float s = out_b[t];
  for (int c = 0; c < 128; ++c) s += out_w[t * 128 + c] * dl[c];
  cb[(b << 7) + t] = s;
  if (b == 0 && t < 4) wts[t] = (t == 0) ? w0 : (t == 1) ? w1 : (t == 2) ? w2 : w3;
}

// ---------- K6 v3: 9x9 conv, 32x128 tile, 4x4 outputs/thread, row-streaming ----------
template <int CPS>  // channels per split
__global__ __launch_bounds__(256) void k6_conv(const float* __restrict__ x,
                                               const float* __restrict__ saw,
                                               float* __restrict__ smap_part) {
  __shared__ float tile[40 * 136];
  int tid = threadIdx.x;
  int yt = blockIdx.x;      // 0..3 (32-row tiles)
  int b = blockIdx.y;
  int split = blockIdx.z;
  int y0 = yt << 5;
  int rg = tid >> 5;        // 0..7  -> 4 output rows each
  int cg = tid & 31;        // 0..31 -> 4 output cols each
  int r0 = rg << 2;
  int px0 = cg << 2;
  float acc[4][4];
#pragma unroll
  for (int i = 0; i < 4; ++i)
#pragma unroll
    for (int j = 0; j < 4; ++j) acc[i][j] = 0.f;
  const float* xb = x + (size_t)b * C_ * HW_;
  int c_lo = split * CPS;

  for (int ci = 0; ci < CPS; ++ci) {
    int c = c_lo + ci;
    const float* xc = xb + (size_t)c * HW_;
    __syncthreads();  // previous compute done before overwriting tile
    // stage 40 x 136 halo tile (full width), f4-aligned, all-or-nothing OOB
    for (int idx = tid; idx < 1360; idx += 256) {
      int row = idx / 34, c4 = idx - row * 34;
      int gy = y0 - 4 + row;
      int gx = (c4 << 2) - 4;
      float4 v = make_float4(0.f, 0.f, 0.f, 0.f);
      if (gy >= 0 && gy < 128 && gx >= 0 && gx <= 124)
        v = *(const float4*)(xc + gy * W_ + gx);
      *(float4*)(tile + row * 136 + (c4 << 2)) = v;
    }
    __syncthreads();
    const float* wrow = saw + c * 81;
#pragma unroll
    for (int ir = 0; ir < 12; ++ir) {
      const float* tp = tile + (r0 + ir) * 136 + px0;
      float4 u0 = *(const float4*)tp;
      float4 u1 = *(const float4*)(tp + 4);
      float4 u2 = *(const float4*)(tp + 8);
      float rowv[12] = {u0.x, u0.y, u0.z, u0.w, u1.x, u1.y, u1.z, u1.w,
                        u2.x, u2.y, u2.z, u2.w};
#pragma unroll
      for (int i = 0; i < 4; ++i) {
        int dy = ir - i;
        if (dy < 0 || dy > 8) continue;  // compile-time folded (ir, i const)
#pragma unroll
        for (int dx = 0; dx < 9; ++dx) {
          float wv = wrow[dy * 9 + dx];
#pragma unroll
          for (int j = 0; j < 4; ++j)
            acc[i][j] = fmaf(wv, rowv[dx + j], acc[i][j]);
        }
      }
    }
  }
  float* op = smap_part + ((size_t)(split * B_ + b)) * HW_ + (y0 + r0) * W_ + px0;
#pragma unroll
  for (int i = 0; i < 4; ++i)
    *(float4*)(op + (size_t)i * W_) = make_float4(acc[i][0], acc[i][1], acc[i][2], acc[i][3]);
}

// ---------- K6b: s[b,p] = wts[1] * sigmoid(sum_parts + sa_b) ----------
template <int NS>
__global__ __launch_bounds__(256) void k6b_gate(const float* __restrict__ smap_part,
                                                const float* __restrict__ wts,
                                                const float* __restrict__ sab,
                                                float* __restrict__ s) {
  int i = (blockIdx.x * 256 + threadIdx.x) << 2;
  float w1 = wts[1];
  float bb = sab[0];
  float4 a = *(const float4*)(smap_part + i);
#pragma unroll
  for (int j = 1; j < NS; ++j) {
    float4 t4 = *(const float4*)(smap_part + (size_t)j * 262144 + i);
    a.x += t4.x; a.y += t4.y; a.z += t4.z; a.w += t4.w;
  }
  float4 r;
  r.x = w1 / (1.f + __expf(-(a.x + bb)));
  r.y = w1 / (1.f + __expf(-(a.y + bb)));
  r.z = w1 / (1.f + __expf(-(a.z + bb)));
  r.w = w1 / (1.f + __expf(-(a.w + bb)));
  *(float4*)(s + i) = r;
}

// ---------- K7a: transpose out_w [o][c] -> wt [c][o] ----------
__global__ __launch_bounds__(256) void k7a_transpose(const float* __restrict__ w,
                                                     float* __restrict__ wt) {
  __shared__ float t[32][33];
  int bx = blockIdx.x & 3, by = blockIdx.x >> 2;  // 4x4 grid of 32x32 tiles
  int lx = threadIdx.x & 31, ly = threadIdx.x >> 5;  // 32 x 8
#pragma unroll
  for (int j = 0; j < 4; ++j)
    t[ly + j * 8][lx] = w[(by * 32 + ly + j * 8) * 128 + bx * 32 + lx];
  __syncthreads();
#pragma unroll
  for (int j = 0; j < 4; ++j)
    wt[(bx * 32 + ly + j * 8) * 128 + by * 32 + lx] = t[lx][ly + j * 8];
}

// ---------- K7 v2: out[b,o,p] = sum_c Wt[c,o]*x[b,c,p]*(g[b,c]+s[b,p]) + cb[b,o] ----------
// W read from global (L1 broadcast); only x-tile in LDS. No VGPR cap -> no spill.
__global__ __launch_bounds__(256) void k7_gemm(const float* __restrict__ x,
                                               const float* __restrict__ wt,
                                               const float* __restrict__ g,
                                               const float* __restrict__ s,
                                               const float* __restrict__ cb,
                                               float* __restrict__ out) {
  __shared__ float xm[64 * 128];  // [c_local][p]
  int tid = threadIdx.x;
  int b = blockIdx.x >> 7;
  int pt = blockIdx.x & 127;
  int p0 = pt << 7;
  const float* xb = x + (size_t)b * C_ * HW_ + p0;
  const float* sb = s + b * HW_ + p0;
  int pg = tid & 15, og = tid >> 4;
  int o0 = og << 3;
  int ppA = pg << 2;
  int ppB = 64 + (pg << 2);
  float acc[8][8];
#pragma unroll
  for (int i = 0; i < 8; ++i)
#pragma unroll
    for (int j = 0; j < 8; ++j) acc[i][j] = 0.f;
  int sp4 = (tid & 31) << 2;
  int crow = tid >> 5;  // 0..7
  float4 sv = *(const float4*)(sb + sp4);
  for (int chunk = 0; chunk < 2; ++chunk) {
    int cbase = chunk << 6;
    __syncthreads();  // previous compute done before restaging xm
#pragma unroll
    for (int pass = 0; pass < 8; ++pass) {
      int cl = (pass << 3) + crow;
      int c = cbase + cl;
      float4 v = *(const float4*)(xb + (size_t)c * HW_ + sp4);
      float gc = g[(b << 7) + c];
      float4 r;
      r.x = v.x * (gc + sv.x);
      r.y = v.y * (gc + sv.y);
      r.z = v.z * (gc + sv.z);
      r.w = v.w * (gc + sv.w);
      *(float4*)(xm + (cl << 7) + sp4) = r;
    }
    __syncthreads();
#pragma unroll 4
    for (int cl = 0; cl < 64; ++cl) {
      const float* wp = wt + ((size_t)(cbase + cl) << 7) + o0;
      float4 wa = *(const float4*)wp;
      float4 wb = *(const float4*)(wp + 4);
      const float* xrow = xm + (cl << 7);
      float4 xa = *(const float4*)(xrow + ppA);
      float4 xb4 = *(const float4*)(xrow + ppB);
      float wv[8] = {wa.x, wa.y, wa.z, wa.w, wb.x, wb.y, wb.z, wb.w};
      float xv[8] = {xa.x, xa.y, xa.z, xa.w, xb4.x, xb4.y, xb4.z, xb4.w};
#pragma unroll
      for (int i = 0; i < 8; ++i)
#pragma unroll
        for (int j = 0; j < 8; ++j) acc[i][j] = fmaf(wv[i], xv[j], acc[i][j]);
    }
  }
  size_t obase = ((size_t)((b << 7) + o0)) * HW_ + p0;
#pragma unroll
  for (int i = 0; i < 8; ++i) {
    float cv = cb[(b << 7) + o0 + i];
    float4 r0 = make_float4(acc[i][0] + cv, acc[i][1] + cv, acc[i][2] + cv, acc[i][3] + cv);
    float4 r1 = make_float4(acc[i][4] + cv, acc[i][5] + cv, acc[i][6] + cv, acc[i][7] + cv);
    *(float4*)(out + obase + (size_t)i * HW_ + ppA) = r0;
    *(float4*)(out + obase + (size_t)i * HW_ + ppB) = r1;
  }
}

extern "C" void kernel_launch(void* const* d_in, const int* in_sizes, int n_in,
                              void* d_out, int out_size, void* d_ws, size_t ws_size,
                              hipStream_t stream) {
  const float* x       = (const float*)d_in[0];
  const float* ca_w1   = (const float*)d_in[1];
  const float* ca_b1   = (const float*)d_in[2];
  const float* ca_w2   = (const float*)d_in[3];
  const float* ca_b2   = (const float*)d_in[4];
  const float* sa_w    = (const float*)d_in[5];
  const float* sa_b    = (const float*)d_in[6];
  const float* fa_w1   = (const float*)d_in[7];
  const float* fa_b1   = (const float*)d_in[8];
  const float* fa_w2   = (const float*)d_in[9];
  const float* fa_b2   = (const float*)d_in[10];
  const float* gc_mw   = (const float*)d_in[11];
  const float* gc_mb   = (const float*)d_in[12];
  const float* gc_t1w  = (const float*)d_in[13];
  const float* gc_t1b  = (const float*)d_in[14];
  const float* gc_lng  = (const float*)d_in[15];
  const float* gc_lnb  = (const float*)d_in[16];
  const float* gc_t2w  = (const float*)d_in[17];
  const float* gc_t2b  = (const float*)d_in[18];
  const float* alpha   = (const float*)d_in[19];
  const float* out_w   = (const float*)d_in[20];
  const float* out_b   = (const float*)d_in[21];
  float* out = (float*)d_out;
  float* ws = (float*)d_ws;

  float* sarr = ws + OFF_SARR;
  float* gap  = ws + OFF_GAP;
  float* favg = ws + OFF_FAVG;
  float* ctx  = ws + OFF_CTX;
  float* g    = ws + OFF_G;
  float* cb   = ws + OFF_CB;
  float* wts  = ws + OFF_WTS;
  float* pmax = ws + OFF_PMAX;
  float* psum = ws + OFF_PSUM;
  float* smx  = ws + OFF_SMX;
  float* sinv = ws + OFF_SINV;
  float* wt   = ws + OFF_WT;
  float* m    = ws + OFF_M;
  float* s    = ws + OFF_S;
  float* smap = ws + OFF_SMAP;

  size_t need16 = (size_t)(OFF_SMAP + 16 * 262144) * sizeof(float);
  size_t need8  = (size_t)(OFF_SMAP + 8 * 262144) * sizeof(float);

  k0_sarr<<<1, 128, 0, stream>>>(sarr);
  k1_planered<<<2048, 256, 0, stream>>>(x, sarr, gap, favg);
  k2_masklogit<<<256, 256, 0, stream>>>(x, gc_mw, gc_mb, m);
  k3a_part<<<256, 256, 0, stream>>>(m, pmax, psum);
  k3b_comb<<<1, 256, 0, stream>>>(pmax, psum, smx, sinv);
  k3c_norm<<<256, 256, 0, stream>>>(m, smx, sinv);
  k4_ctx<<<2048, 256, 0, stream>>>(x, m, ctx);
  k5_mlp<<<16, 128, 0, stream>>>(gap, favg, ctx, ca_w1, ca_b1, ca_w2, ca_b2,
                                 fa_w1, fa_b1, fa_w2, fa_b2, gc_t1w, gc_t1b,
                                 gc_lng, gc_lnb, gc_t2w, gc_t2b, alpha,
                                 out_w, out_b, g, cb, wts);
  k7a_transpose<<<16, 256, 0, stream>>>(out_w, wt);
  if (ws_size >= need16) {
    k6_conv<8><<<dim3(4, 16, 16), 256, 0, stream>>>(x, sa_w, smap);
    k6b_gate<16><<<256, 256, 0, stream>>>(smap, wts, sa_b, s);
  } else if (ws_size >= need8) {
    k6_conv<16><<<dim3(4, 16, 8), 256, 0, stream>>>(x, sa_w, smap);
    k6b_gate<8><<<256, 256, 0, stream>>>(smap, wts, sa_b, s);
  } else {
    k6_conv<32><<<dim3(4, 16, 4), 256, 0, stream>>>(x, sa_w, smap);
    k6b_gate<4><<<256, 256, 0, stream>>>(smap, wts, sa_b, s);
  }
  k7_gemm<<<2048, 256, 0, stream>>>(x, wt, g, s, cb, out);
}